// Round 3
// baseline (17593.134 us; speedup 1.0000x reference)
//
#include <hip/hip_runtime.h>
#include <hip/hip_bf16.h>
#include <cstdint>
#include <cstddef>

// BiLSTM-CRF forward + Viterbi decode, T=4096, E=300, H2=256, K=32.
//   K1 zx_gemm    : zx[t] = Wih @ embed[token] + b (both dirs, batched)
//   K2 lstm_kernel: 4 CUs/dir, Whh in f16 VGPRs (64 regs/lane, asm-pinned —
//                   R2's fp32 128-reg version got remat'ed to L2, VGPR=96).
//                   Barrier-free dataflow: h exchanged as 8-byte qwords
//                   [tag u32 | f16x2 pair] via relaxed agent atomics; each
//                   16-lane DPP group owns all 4 gates of 2 h-elems, so gates
//                   are computed in-lane after a 4-op circular DPP reduce.
//   K3 feat_kernel: feats = [hf|hb] @ W_out^T + b_out (h history bf16)
//   K4 viterbi_fwd: SINGLE WAVE, fv in registers, 16 bpermute gathers +
//                   register argmax tree per step (no LDS, no barriers).
//   K5 compose, K6 backtrace: unchanged.

#define T_LEN 4096
#define E_DIM 300
#define H2 256
#define G4 1024
#define KTAGS 32
#define START_TAG 30
#define STOP_TAG 31
#define NEGV (-10000.0f)

typedef _Float16 h2_t __attribute__((ext_vector_type(2)));

__device__ __forceinline__ float fast_sigmoid(float x) {
  return __builtin_amdgcn_rcpf(1.0f + __expf(-x));
}
__device__ __forceinline__ float fast_tanh(float x) {
  return 1.0f - 2.0f * __builtin_amdgcn_rcpf(__expf(2.0f * x) + 1.0f);
}

template <int CTRL>
__device__ __forceinline__ float row_ror_add(float x) {
  int v = __builtin_amdgcn_update_dpp(0, __float_as_int(x), CTRL, 0xF, 0xF, true);
  return x + __int_as_float(v);
}

__device__ __forceinline__ uint32_t pack_bf16(float a, float b) {
  uint32_t ua = __float_as_uint(a), ub = __float_as_uint(b);
  ua = (ua + 0x7FFFu + ((ua >> 16) & 1u)) >> 16;          // RNE, low half = a
  ub = (ub + 0x7FFFu + ((ub >> 16) & 1u)) & 0xFFFF0000u;  // high half = b
  return ua | ub;
}

// ---------------- K1: input projection GEMM ----------------
__global__ __launch_bounds__(256) void zx_gemm(
    const int* __restrict__ sent, const float* __restrict__ embed,
    const float* __restrict__ Wih_f, const float* __restrict__ b_f,
    const float* __restrict__ Wih_b, const float* __restrict__ b_b,
    float* __restrict__ zxF, float* __restrict__ zxB)
{
  const int dir = blockIdx.y;
  const int t0 = blockIdx.x * 8;
  const float* __restrict__ Wih = dir ? Wih_b : Wih_f;
  const float* __restrict__ bias = dir ? b_b : b_f;
  float* __restrict__ zx = dir ? zxB : zxF;

  __shared__ __align__(16) float xs[8 * E_DIM];
  const int tid = threadIdx.x;
  for (int ti = 0; ti < 8; ++ti) {
    int p = t0 + ti;
    int tok = sent[dir ? (T_LEN - 1 - p) : p];
    const float* er = embed + (size_t)tok * E_DIM;
    for (int k = tid; k < E_DIM; k += 256) xs[ti * E_DIM + k] = er[k];
  }
  __syncthreads();

  const int r = tid;
  float acc[4][8];
#pragma unroll
  for (int g = 0; g < 4; ++g) {
    float bv = bias[g * 256 + r];
#pragma unroll
    for (int ti = 0; ti < 8; ++ti) acc[g][ti] = bv;
  }
  const float4* w0p = (const float4*)(Wih + (size_t)(r) * E_DIM);
  const float4* w1p = (const float4*)(Wih + (size_t)(256 + r) * E_DIM);
  const float4* w2p = (const float4*)(Wih + (size_t)(512 + r) * E_DIM);
  const float4* w3p = (const float4*)(Wih + (size_t)(768 + r) * E_DIM);
  for (int k4 = 0; k4 < E_DIM / 4; ++k4) {
    float4 w0 = w0p[k4], w1 = w1p[k4], w2 = w2p[k4], w3 = w3p[k4];
#pragma unroll
    for (int ti = 0; ti < 8; ++ti) {
      float4 x4 = *(const float4*)(xs + ti * E_DIM + k4 * 4);
      acc[0][ti] += w0.x * x4.x + w0.y * x4.y + w0.z * x4.z + w0.w * x4.w;
      acc[1][ti] += w1.x * x4.x + w1.y * x4.y + w1.z * x4.z + w1.w * x4.w;
      acc[2][ti] += w2.x * x4.x + w2.y * x4.y + w2.z * x4.z + w2.w * x4.w;
      acc[3][ti] += w3.x * x4.x + w3.y * x4.y + w3.z * x4.z + w3.w * x4.w;
    }
  }
#pragma unroll
  for (int g = 0; g < 4; ++g)
#pragma unroll
    for (int ti = 0; ti < 8; ++ti)
      zx[(size_t)(t0 + ti) * G4 + g * 256 + r] = acc[g][ti];
}

// ---------------- K2: barrier-free dataflow LSTM ----------------
// ctl ints: [0..7]=xcdCnt [8]=dirCnt [16..23]=xcdDir
// hxq: [dir][parity][128] qwords, qword = (tag u32)<<32 | f16x2(h[2p],h[2p+1])
__global__ __launch_bounds__(512, 2) void lstm_kernel(
    const float* __restrict__ Whh_f, const float* __restrict__ Whh_b,
    const float* __restrict__ h0, const float* __restrict__ c0,
    const float* __restrict__ zxF, const float* __restrict__ zxB,
    uint64_t* __restrict__ hxq, uint32_t* __restrict__ hhF32,
    uint32_t* __restrict__ hhB32, int* __restrict__ ctl)
{
  __shared__ int sh_dir, sh_role;
  const int tid = threadIdx.x;

  if (tid == 0) {
    int xcd = (int)(__builtin_amdgcn_s_getreg(20 | (3 << 11)) & 7);  // HW_REG_XCC_ID
    int* xcdCnt = ctl;
    int* dirCnt = ctl + 8;
    int* xcdDir = ctl + 16;
    int rr = atomicAdd(&xcdCnt[xcd], 1);
    if (rr == 3) {
      int idx = atomicAdd(dirCnt, 1);
      __hip_atomic_store(&xcdDir[xcd], (idx < 2) ? (idx + 1) : 3,
                         __ATOMIC_RELEASE, __HIP_MEMORY_SCOPE_AGENT);
    }
    int dir = -1;
    if (rr < 4) {
      int v = 0;
      long g = 0;
      do {
        v = __hip_atomic_load(&xcdDir[xcd], __ATOMIC_ACQUIRE, __HIP_MEMORY_SCOPE_AGENT);
      } while (v == 0 && ++g < (1L << 31));
      if (v >= 1 && v <= 2) dir = v - 1;
    }
    sh_dir = dir;
    sh_role = rr;
  }
  __syncthreads();
  const int d = sh_dir;
  const int r = sh_role;
  if (d < 0) return;

  const float* __restrict__ Whh = d ? Whh_b : Whh_f;
  const float* __restrict__ zxd = d ? zxB : zxF;
  uint32_t* __restrict__ hh32 = d ? hhB32 : hhF32;

  const int ks = tid & 15;        // kslice 0..15 (16 lanes of a DPP row)
  const int q = tid >> 4;         // rgroup 0..31
  const int pe = r * 32 + q;      // global h-pair 0..127
  const int k0 = 2 * pe;          // global h-elem base

  // weights: 8 rows (4 gates x 2 elems) x 16 k, f16 -> 64 VGPRs, asm-pinned
  int wi[64];
#pragma unroll
  for (int m = 0; m < 8; ++m) {
    int e = m & 1, g = m >> 1;
    int grow = g * 256 + k0 + e;
    const float4* wp = (const float4*)(Whh + (size_t)grow * H2 + ks * 16);
#pragma unroll
    for (int i4 = 0; i4 < 4; ++i4) {
      float4 v = wp[i4];
      wi[m * 8 + i4 * 2] = __builtin_bit_cast(int, __builtin_amdgcn_cvt_pkrtz(v.x, v.y));
      wi[m * 8 + i4 * 2 + 1] = __builtin_bit_cast(int, __builtin_amdgcn_cvt_pkrtz(v.z, v.w));
    }
  }
#pragma unroll
  for (int i = 0; i < 64; ++i) asm volatile("" : "+v"(wi[i]));  // no remat/spill

  float c0r = c0[d * H2 + k0];
  float c1r = c0[d * H2 + k0 + 1];

  // seed h(t=-1) -> parity 0, tag 0
  if (ks == 0) {
    uint32_t hp = __builtin_bit_cast(uint32_t,
        __builtin_amdgcn_cvt_pkrtz(h0[d * H2 + k0], h0[d * H2 + k0 + 1]));
    __hip_atomic_store(&hxq[((size_t)d * 2 + 0) * 128 + pe], (uint64_t)hp,
                       __ATOMIC_RELAXED, __HIP_MEMORY_SCOPE_AGENT);
  }

  // zx prefetch for t=0 (zcur[m], m = g*2+e)
  float zcur[8], znext[8];
#pragma unroll
  for (int g = 0; g < 4; ++g) {
    float2 zl = *(const float2*)(zxd + (size_t)0 * G4 + g * 256 + k0);
    zcur[g * 2] = zl.x;
    zcur[g * 2 + 1] = zl.y;
  }

  for (int t = 0; t < T_LEN; ++t) {
    const uint64_t* qin = hxq + ((size_t)d * 2 + (t & 1)) * 128;
    uint64_t qd[8];
#pragma unroll
    for (int i = 0; i < 8; ++i)
      qd[i] = __hip_atomic_load(&qin[ks * 8 + i], __ATOMIC_RELAXED, __HIP_MEMORY_SCOPE_AGENT);
#pragma unroll
    for (int i = 0; i < 8; ++i) {
      int g = 0;
      while ((uint32_t)(qd[i] >> 32) != (uint32_t)t) {
        qd[i] = __hip_atomic_load(&qin[ks * 8 + i], __ATOMIC_RELAXED, __HIP_MEMORY_SCOPE_AGENT);
        if (++g > (1 << 20)) break;  // bailout: terminate over hang
      }
    }

    // matvec: 8 rows x 8 fdot2 (16 f16 k each)
    float acc[8];
#pragma unroll
    for (int m = 0; m < 8; ++m) {
      float a = 0.f;
#pragma unroll
      for (int i = 0; i < 8; ++i) {
        h2_t hv = __builtin_bit_cast(h2_t, (uint32_t)qd[i]);
        h2_t wv = __builtin_bit_cast(h2_t, wi[m * 8 + i]);
        a = __builtin_amdgcn_fdot2(wv, hv, a, false);
      }
      acc[m] = a;
    }
    // circular reduce over 16 kslices (all lanes end with full sums)
#pragma unroll
    for (int m = 0; m < 8; ++m) {
      acc[m] = row_ror_add<0x128>(acc[m]);
      acc[m] = row_ror_add<0x124>(acc[m]);
      acc[m] = row_ror_add<0x122>(acc[m]);
      acc[m] = row_ror_add<0x121>(acc[m]);
    }

    // prefetch zx for t+1 (overlaps gate math)
    int tn = (t + 1 < T_LEN) ? t + 1 : t;
#pragma unroll
    for (int g = 0; g < 4; ++g) {
      float2 zl = *(const float2*)(zxd + (size_t)tn * G4 + g * 256 + k0);
      znext[g * 2] = zl.x;
      znext[g * 2 + 1] = zl.y;
    }

    // gates, in-lane (redundant across the 16 lanes; deterministic)
    float zi0 = acc[0] + zcur[0], zi1 = acc[1] + zcur[1];
    float zf0 = acc[2] + zcur[2], zf1 = acc[3] + zcur[3];
    float zg0 = acc[4] + zcur[4], zg1 = acc[5] + zcur[5];
    float zo0 = acc[6] + zcur[6], zo1 = acc[7] + zcur[7];
    c0r = fast_sigmoid(zf0) * c0r + fast_sigmoid(zi0) * fast_tanh(zg0);
    c1r = fast_sigmoid(zf1) * c1r + fast_sigmoid(zi1) * fast_tanh(zg1);
    float hv0 = fast_sigmoid(zo0) * fast_tanh(c0r);
    float hv1 = fast_sigmoid(zo1) * fast_tanh(c1r);

    if (ks == 0) {
      uint32_t hp = __builtin_bit_cast(uint32_t, __builtin_amdgcn_cvt_pkrtz(hv0, hv1));
      uint64_t qw = ((uint64_t)(uint32_t)(t + 1) << 32) | hp;
      __hip_atomic_store(&hxq[((size_t)d * 2 + ((t + 1) & 1)) * 128 + pe], qw,
                         __ATOMIC_RELAXED, __HIP_MEMORY_SCOPE_AGENT);
      hh32[(size_t)t * 128 + pe] = pack_bf16(hv0, hv1);
    }
#pragma unroll
    for (int m = 0; m < 8; ++m) zcur[m] = znext[m];
  }
}

// ---------------- K3: feats = [hf|hb] @ W_out^T + b_out ----------------
__global__ __launch_bounds__(256) void feat_kernel(
    const __hip_bfloat16* __restrict__ hhF, const __hip_bfloat16* __restrict__ hhB,
    const float* __restrict__ W_out, const float* __restrict__ b_out,
    float* __restrict__ feats)
{
  const int p0 = blockIdx.x * 8;
  const int tid = threadIdx.x;
  __shared__ float hs[8 * 520];
#define HIDX(pos, k) ((pos) * 520 + (k) + ((k) >> 6))
  for (int idx = tid; idx < 2048; idx += 256) {
    int pos = idx >> 8, k = idx & 255;
    hs[HIDX(pos, k)] = (float)hhF[(size_t)(p0 + pos) * H2 + k];
    hs[HIDX(pos, 256 + k)] = (float)hhB[(size_t)(T_LEN - 1 - (p0 + pos)) * H2 + k];
  }
  __syncthreads();

  const int tag = tid >> 3;
  const int kc = tid & 7;
  float4 w4[16];
  const float4* wp = (const float4*)(W_out + tag * 512 + kc * 64);
#pragma unroll
  for (int i = 0; i < 16; ++i) w4[i] = wp[i];
  const float bo = b_out[tag];

#pragma unroll
  for (int pos = 0; pos < 8; ++pos) {
    const float* hp = hs + pos * 520 + kc * 64 + kc;
    float a = 0.f;
#pragma unroll
    for (int i = 0; i < 16; ++i) {
      float4 w = w4[i];
      a += w.x * hp[i * 4] + w.y * hp[i * 4 + 1] + w.z * hp[i * 4 + 2] + w.w * hp[i * 4 + 3];
    }
    a += __shfl_xor(a, 1);
    a += __shfl_xor(a, 2);
    a += __shfl_xor(a, 4);
    if (kc == 0) feats[(size_t)(p0 + pos) * KTAGS + tag] = a + bo;
  }
}

// ---------------- K4: single-wave Viterbi forward ----------------
__global__ __launch_bounds__(64) void viterbi_fwd(
    const float* __restrict__ feats, const float* __restrict__ trans,
    unsigned char* __restrict__ bptr, float* __restrict__ score_out,
    int* __restrict__ best_out)
{
  const int ln = threadIdx.x;
  const int i = ln & 31;   // my tag (replicated in both halves)
  const int jb = ln >> 5;  // j-block: lanes handle j = jb*16 + s

  float Tj[16];
#pragma unroll
  for (int s = 0; s < 16; ++s) Tj[s] = trans[i * 32 + jb * 16 + s];

  float fv = (i == START_TAG) ? 0.0f : NEGV;
  float pf = feats[i];

  for (int t = 0; t < T_LEN; ++t) {
    float cv[16];
    int cj[16];
#pragma unroll
    for (int s = 0; s < 16; ++s) {
      cv[s] = __shfl(fv, jb * 16 + s) + Tj[s];
      cj[s] = jb * 16 + s;
    }
    // register argmax tree; strict > keeps lower j on ties (numpy rule)
#pragma unroll
    for (int st = 1; st < 16; st <<= 1)
#pragma unroll
      for (int s = 0; s < 16; s += 2 * st)
        if (cv[s + st] > cv[s]) { cv[s] = cv[s + st]; cj[s] = cj[s + st]; }
    float v = cv[0];
    int bj = cj[0];
    float ov = __shfl_xor(v, 32);
    int oj = __shfl_xor(bj, 32);
    if (ov > v || (ov == v && oj < bj)) { v = ov; bj = oj; }

    float f = pf;
    int tn = (t + 1 < T_LEN) ? t + 1 : t;
    pf = feats[(size_t)tn * KTAGS + i];  // prefetch
    fv = v + f;
    if (jb == 0) bptr[(size_t)t * KTAGS + i] = (unsigned char)bj;
  }

  // terminal: fv + transitions[STOP]; argmax over tags (first-index ties)
  float v = fv + trans[STOP_TAG * 32 + i];
  int bi = i;
#pragma unroll
  for (int m = 1; m < 32; m <<= 1) {
    float ov = __shfl_xor(v, m);
    int oi = __shfl_xor(bi, m);
    if (ov > v || (ov == v && oi < bi)) { v = ov; bi = oi; }
  }
  if (ln == 0) { score_out[0] = v; best_out[0] = bi; }
}

// ---------------- K5: compose 32-step backtrace maps ----------------
__global__ __launch_bounds__(64) void vit_compose(
    const unsigned char* __restrict__ bptr, unsigned char* __restrict__ fmap)
{
  const int m = blockIdx.x;
  __shared__ unsigned char B[32 * 32];
  const int tid = threadIdx.x;
  const uint32_t* src = (const uint32_t*)(bptr + (size_t)m * 1024);
  uint32_t* dstw = (uint32_t*)B;
  for (int idx = tid; idx < 256; idx += 64) dstw[idx] = src[idx];
  __syncthreads();
  if (tid < 32) {
    int y = tid;
#pragma unroll
    for (int tt = 31; tt >= 0; --tt) y = B[tt * 32 + y];
    fmap[m * 32 + tid] = (unsigned char)y;
  }
}

// ---------------- K6: boundary walk + parallel expansion ----------------
__global__ __launch_bounds__(256) void vit_backtrace(
    const unsigned char* __restrict__ bptr, const unsigned char* __restrict__ fmap,
    const int* __restrict__ best, float* __restrict__ path_out)
{
  __shared__ unsigned char F[128 * 32];
  __shared__ unsigned char bound[128];
  const int tid = threadIdx.x;
  const uint32_t* src = (const uint32_t*)fmap;
  uint32_t* dstw = (uint32_t*)F;
  for (int idx = tid; idx < 1024; idx += 256) dstw[idx] = src[idx];
  __syncthreads();
  if (tid == 0) {
    int y = best[0];
    bound[127] = (unsigned char)y;
    for (int m = 127; m >= 1; --m) {
      y = F[m * 32 + y];
      bound[m - 1] = (unsigned char)y;
    }
  }
  __syncthreads();
  if (tid < 128) {
    const int m = tid;
    int y = bound[m];
    path_out[m * 32 + 31] = (float)y;
    for (int tt = 30; tt >= 0; --tt) {
      y = bptr[(size_t)(m * 32 + tt + 1) * 32 + y];
      path_out[m * 32 + tt] = (float)y;
    }
  }
}

extern "C" void kernel_launch(void* const* d_in, const int* in_sizes, int n_in,
                              void* d_out, int out_size, void* d_ws, size_t ws_size,
                              hipStream_t stream)
{
  const int* sent    = (const int*)d_in[0];
  const float* embed = (const float*)d_in[1];
  const float* Wih_f = (const float*)d_in[2];
  const float* Whh_f = (const float*)d_in[3];
  const float* b_f   = (const float*)d_in[4];
  const float* Wih_b = (const float*)d_in[5];
  const float* Whh_b = (const float*)d_in[6];
  const float* b_b   = (const float*)d_in[7];
  const float* W_out = (const float*)d_in[8];
  const float* b_out = (const float*)d_in[9];
  const float* trans = (const float*)d_in[10];
  const float* h0    = (const float*)d_in[11];
  const float* c0    = (const float*)d_in[12];

  float* W = (float*)d_ws;
  float* zxF = W;                                    // 16 MB
  float* zxB = zxF + (size_t)T_LEN * G4;             // 16 MB
  float* feats = zxB + (size_t)T_LEN * G4;           // 512 KB
  uint32_t* hhF32 = (uint32_t*)(feats + (size_t)T_LEN * KTAGS);  // 2 MB (bf16 pairs)
  uint32_t* hhB32 = hhF32 + (size_t)T_LEN * 128;     // 2 MB
  uint64_t* hxq = (uint64_t*)(hhB32 + (size_t)T_LEN * 128);  // 2*2*128 qwords = 4 KB
  int* ctl = (int*)(hxq + 512);                      // 4 KB control
  int* bestIdx = ctl + 1024;
  unsigned char* bptr = (unsigned char*)(bestIdx + 16);  // 128 KB
  unsigned char* fmap = bptr + (size_t)T_LEN * KTAGS;    // 4 KB

  float* out = (float*)d_out;  // out[0]=path_score, out[1..4096]=path tags

  hipMemsetAsync(ctl, 0, 4096, stream);  // election counters

  zx_gemm<<<dim3(T_LEN / 8, 2), 256, 0, stream>>>(sent, embed, Wih_f, b_f, Wih_b, b_b, zxF, zxB);
  lstm_kernel<<<64, 512, 0, stream>>>(Whh_f, Whh_b, h0, c0, zxF, zxB, hxq, hhF32, hhB32, ctl);
  feat_kernel<<<T_LEN / 8, 256, 0, stream>>>((const __hip_bfloat16*)hhF32,
                                             (const __hip_bfloat16*)hhB32,
                                             W_out, b_out, feats);
  viterbi_fwd<<<1, 64, 0, stream>>>(feats, trans, bptr, out, bestIdx);
  vit_compose<<<128, 64, 0, stream>>>(bptr, fmap);
  vit_backtrace<<<1, 256, 0, stream>>>(bptr, fmap, bestIdx, out + 1);
}

// Round 4
// 10200.190 us; speedup vs baseline: 1.7248x; 1.7248x over previous
//
#include <hip/hip_runtime.h>
#include <hip/hip_bf16.h>
#include <cstdint>
#include <cstddef>

// BiLSTM-CRF forward + Viterbi decode, T=4096, E=300, H2=256, K=32.
//   K1 zx_gemm    : zx[t] = Wih @ embed[token] + b (both dirs, batched)
//   K2 lstm_kernel: ONE CU PER DIRECTION (grid=2, 512 thr). Whole Whh in f16
//                   on-CU: 6/8 per-thread row-slices in 192 VGPRs (384 KB),
//                   o-gate rows in 136 KB LDS (68-dw stride -> 17*lane mod 32
//                   start banks = conflict-free). h in LDS f16x2, broadcast
//                   reads. One __syncthreads per step; ZERO cross-CU sync
//                   (R2/R3's per-step device-scope exchange gave 15-45 ms
//                   with 36 GB poll/spill fetch — structurally removed).
//   K3 feat_kernel: feats = [hf|hb] @ W_out^T + b_out (h history bf16)
//   K4 viterbi_fwd: single wave, fv in registers, register argmax tree
//   K5 compose, K6 backtrace: parallel backtrace reconstruction.

#define T_LEN 4096
#define E_DIM 300
#define H2 256
#define G4 1024
#define KTAGS 32
#define START_TAG 30
#define STOP_TAG 31
#define NEGV (-10000.0f)

typedef _Float16 h2_t __attribute__((ext_vector_type(2)));

__device__ __forceinline__ float fast_sigmoid(float x) {
  return __builtin_amdgcn_rcpf(1.0f + __expf(-x));
}
__device__ __forceinline__ float fast_tanh(float x) {
  return 1.0f - 2.0f * __builtin_amdgcn_rcpf(__expf(2.0f * x) + 1.0f);
}

template <int CTRL>
__device__ __forceinline__ float quad_add(float x) {
  int v = __builtin_amdgcn_update_dpp(0, __float_as_int(x), CTRL, 0xF, 0xF, true);
  return x + __int_as_float(v);
}

__device__ __forceinline__ int pk16(float a, float b) {
  return __builtin_bit_cast(int, __builtin_amdgcn_cvt_pkrtz(a, b));
}

__device__ __forceinline__ uint32_t pack_bf16(float a, float b) {
  uint32_t ua = __float_as_uint(a), ub = __float_as_uint(b);
  ua = (ua + 0x7FFFu + ((ua >> 16) & 1u)) >> 16;          // RNE, low half = a
  ub = (ub + 0x7FFFu + ((ub >> 16) & 1u)) & 0xFFFF0000u;  // high half = b
  return ua | ub;
}

// ---------------- K1: input projection GEMM ----------------
__global__ __launch_bounds__(256) void zx_gemm(
    const int* __restrict__ sent, const float* __restrict__ embed,
    const float* __restrict__ Wih_f, const float* __restrict__ b_f,
    const float* __restrict__ Wih_b, const float* __restrict__ b_b,
    float* __restrict__ zxF, float* __restrict__ zxB)
{
  const int dir = blockIdx.y;
  const int t0 = blockIdx.x * 8;
  const float* __restrict__ Wih = dir ? Wih_b : Wih_f;
  const float* __restrict__ bias = dir ? b_b : b_f;
  float* __restrict__ zx = dir ? zxB : zxF;

  __shared__ __align__(16) float xs[8 * E_DIM];
  const int tid = threadIdx.x;
  for (int ti = 0; ti < 8; ++ti) {
    int p = t0 + ti;
    int tok = sent[dir ? (T_LEN - 1 - p) : p];
    const float* er = embed + (size_t)tok * E_DIM;
    for (int k = tid; k < E_DIM; k += 256) xs[ti * E_DIM + k] = er[k];
  }
  __syncthreads();

  const int r = tid;
  float acc[4][8];
#pragma unroll
  for (int g = 0; g < 4; ++g) {
    float bv = bias[g * 256 + r];
#pragma unroll
    for (int ti = 0; ti < 8; ++ti) acc[g][ti] = bv;
  }
  const float4* w0p = (const float4*)(Wih + (size_t)(r) * E_DIM);
  const float4* w1p = (const float4*)(Wih + (size_t)(256 + r) * E_DIM);
  const float4* w2p = (const float4*)(Wih + (size_t)(512 + r) * E_DIM);
  const float4* w3p = (const float4*)(Wih + (size_t)(768 + r) * E_DIM);
  for (int k4 = 0; k4 < E_DIM / 4; ++k4) {
    float4 w0 = w0p[k4], w1 = w1p[k4], w2 = w2p[k4], w3 = w3p[k4];
#pragma unroll
    for (int ti = 0; ti < 8; ++ti) {
      float4 x4 = *(const float4*)(xs + ti * E_DIM + k4 * 4);
      acc[0][ti] += w0.x * x4.x + w0.y * x4.y + w0.z * x4.z + w0.w * x4.w;
      acc[1][ti] += w1.x * x4.x + w1.y * x4.y + w1.z * x4.z + w1.w * x4.w;
      acc[2][ti] += w2.x * x4.x + w2.y * x4.y + w2.z * x4.z + w2.w * x4.w;
      acc[3][ti] += w3.x * x4.x + w3.y * x4.y + w3.z * x4.z + w3.w * x4.w;
    }
  }
#pragma unroll
  for (int g = 0; g < 4; ++g)
#pragma unroll
    for (int ti = 0; ti < 8; ++ti)
      zx[(size_t)(t0 + ti) * G4 + g * 256 + r] = acc[g][ti];
}

// ---------------- K2: single-CU-per-direction LSTM ----------------
// thread (q = tid>>2, kpart = tid&3): owns h-elems {2q, 2q+1}, k-slice
// [kpart*64, kpart*64+64). 8 rows (4 gates x 2 elems): i,f,g in 192 VGPRs,
// o-gate's 2 row-slices in LDS. Quad DPP butterfly reduces the 4-way k-split;
// gates computed redundantly in all 4 quad lanes (deterministic).
__global__ __launch_bounds__(512, 2) void lstm_kernel(
    const float* __restrict__ Whh_f, const float* __restrict__ Whh_b,
    const float* __restrict__ h0, const float* __restrict__ c0,
    const float* __restrict__ zxF, const float* __restrict__ zxB,
    uint32_t* __restrict__ hhF32, uint32_t* __restrict__ hhB32)
{
  const int d = blockIdx.x;
  const float* __restrict__ Whh = d ? Whh_b : Whh_f;
  const float* __restrict__ zxd = d ? zxB : zxF;
  uint32_t* __restrict__ hh32 = d ? hhB32 : hhF32;

  const int tid = threadIdx.x;
  const int kpart = tid & 3;
  const int q = tid >> 2;      // h-pair 0..127
  const int k0 = kpart * 64;

  // o-gate weights: per-thread 64 dw at stride 68 (start bank 17*lane mod 32
  // = bijection over 32 banks -> conflict-free b128)
  __shared__ int wlds[512 * 68];            // 136 KB
  __shared__ __align__(16) int hA[128];     // h as packed f16x2 pairs
  __shared__ __align__(16) int hB[128];

  // --- load + convert weights (one-time) ---
  int wreg[192];  // rows m=0..5 = (gate i,f,g) x (elem 0,1), 32 dw each
#pragma unroll
  for (int m = 0; m < 6; ++m) {
    int g = m >> 1, e = m & 1;
    const float4* wp = (const float4*)(Whh + (size_t)(g * 256 + 2 * q + e) * H2 + k0);
#pragma unroll
    for (int i = 0; i < 16; ++i) {
      float4 v = wp[i];
      wreg[m * 32 + i * 2] = pk16(v.x, v.y);
      wreg[m * 32 + i * 2 + 1] = pk16(v.z, v.w);
    }
  }
  {
    int* wl = wlds + tid * 68;
    for (int e = 0; e < 2; ++e) {
      const float4* wp = (const float4*)(Whh + (size_t)(3 * 256 + 2 * q + e) * H2 + k0);
#pragma unroll
      for (int i = 0; i < 16; ++i) {
        float4 v = wp[i];
        wl[e * 32 + i * 2] = pk16(v.x, v.y);
        wl[e * 32 + i * 2 + 1] = pk16(v.z, v.w);
      }
    }
  }

  float c0r = c0[d * H2 + 2 * q];
  float c1r = c0[d * H2 + 2 * q + 1];
  if (tid < 128) hA[tid] = pk16(h0[d * H2 + 2 * tid], h0[d * H2 + 2 * tid + 1]);
  __syncthreads();

  const float* zp = zxd + 2 * q;          // walks t*G4
  uint32_t* hp = hh32 + q;                // walks t*128
  const int* wl = wlds + tid * 68;

  auto step = [&](const int* hin, int* hout) {
    // zx for this step (consumed at gate time; latency hidden by matvec)
    float2 zi2 = *(const float2*)(zp);
    float2 zf2 = *(const float2*)(zp + 256);
    float2 zg2 = *(const float2*)(zp + 512);
    float2 zo2 = *(const float2*)(zp + 768);

    float acc[8] = {0.f, 0.f, 0.f, 0.f, 0.f, 0.f, 0.f, 0.f};
#pragma unroll
    for (int cc = 0; cc < 4; ++cc) {
      int h8[8], w6[8], w7[8];
      *(int4*)(h8) = *(const int4*)(hin + kpart * 32 + cc * 8);
      *(int4*)(h8 + 4) = *(const int4*)(hin + kpart * 32 + cc * 8 + 4);
      *(int4*)(w6) = *(const int4*)(wl + cc * 8);
      *(int4*)(w6 + 4) = *(const int4*)(wl + cc * 8 + 4);
      *(int4*)(w7) = *(const int4*)(wl + 32 + cc * 8);
      *(int4*)(w7 + 4) = *(const int4*)(wl + 32 + cc * 8 + 4);
#pragma unroll
      for (int j = 0; j < 8; ++j) {
        h2_t hv = __builtin_bit_cast(h2_t, h8[j]);
        acc[0] = __builtin_amdgcn_fdot2(__builtin_bit_cast(h2_t, wreg[0 * 32 + cc * 8 + j]), hv, acc[0], false);
        acc[1] = __builtin_amdgcn_fdot2(__builtin_bit_cast(h2_t, wreg[1 * 32 + cc * 8 + j]), hv, acc[1], false);
        acc[2] = __builtin_amdgcn_fdot2(__builtin_bit_cast(h2_t, wreg[2 * 32 + cc * 8 + j]), hv, acc[2], false);
        acc[3] = __builtin_amdgcn_fdot2(__builtin_bit_cast(h2_t, wreg[3 * 32 + cc * 8 + j]), hv, acc[3], false);
        acc[4] = __builtin_amdgcn_fdot2(__builtin_bit_cast(h2_t, wreg[4 * 32 + cc * 8 + j]), hv, acc[4], false);
        acc[5] = __builtin_amdgcn_fdot2(__builtin_bit_cast(h2_t, wreg[5 * 32 + cc * 8 + j]), hv, acc[5], false);
        acc[6] = __builtin_amdgcn_fdot2(__builtin_bit_cast(h2_t, w6[j]), hv, acc[6], false);
        acc[7] = __builtin_amdgcn_fdot2(__builtin_bit_cast(h2_t, w7[j]), hv, acc[7], false);
      }
    }
    // quad butterfly: every lane gets full k=256 sums
#pragma unroll
    for (int m = 0; m < 8; ++m) {
      acc[m] = quad_add<0xB1>(acc[m]);
      acc[m] = quad_add<0x4E>(acc[m]);
    }
    // gates (redundant across quad — deterministic)
    float zi0 = acc[0] + zi2.x, zi1 = acc[1] + zi2.y;
    float zf0 = acc[2] + zf2.x, zf1 = acc[3] + zf2.y;
    float zg0 = acc[4] + zg2.x, zg1 = acc[5] + zg2.y;
    float zo0 = acc[6] + zo2.x, zo1 = acc[7] + zo2.y;
    c0r = fast_sigmoid(zf0) * c0r + fast_sigmoid(zi0) * fast_tanh(zg0);
    c1r = fast_sigmoid(zf1) * c1r + fast_sigmoid(zi1) * fast_tanh(zg1);
    float hv0 = fast_sigmoid(zo0) * fast_tanh(c0r);
    float hv1 = fast_sigmoid(zo1) * fast_tanh(c1r);
    if (kpart == 0) {
      hout[q] = pk16(hv0, hv1);
      *hp = pack_bf16(hv0, hv1);
    }
    zp += G4;
    hp += 128;
    __syncthreads();
  };

  for (int t = 0; t < T_LEN; t += 2) {
    step(hA, hB);
    step(hB, hA);
  }
}

// ---------------- K3: feats = [hf|hb] @ W_out^T + b_out ----------------
__global__ __launch_bounds__(256) void feat_kernel(
    const __hip_bfloat16* __restrict__ hhF, const __hip_bfloat16* __restrict__ hhB,
    const float* __restrict__ W_out, const float* __restrict__ b_out,
    float* __restrict__ feats)
{
  const int p0 = blockIdx.x * 8;
  const int tid = threadIdx.x;
  __shared__ float hs[8 * 520];
#define HIDX(pos, k) ((pos) * 520 + (k) + ((k) >> 6))
  for (int idx = tid; idx < 2048; idx += 256) {
    int pos = idx >> 8, k = idx & 255;
    hs[HIDX(pos, k)] = (float)hhF[(size_t)(p0 + pos) * H2 + k];
    hs[HIDX(pos, 256 + k)] = (float)hhB[(size_t)(T_LEN - 1 - (p0 + pos)) * H2 + k];
  }
  __syncthreads();

  const int tag = tid >> 3;
  const int kc = tid & 7;
  float4 w4[16];
  const float4* wp = (const float4*)(W_out + tag * 512 + kc * 64);
#pragma unroll
  for (int i = 0; i < 16; ++i) w4[i] = wp[i];
  const float bo = b_out[tag];

#pragma unroll
  for (int pos = 0; pos < 8; ++pos) {
    const float* hpp = hs + pos * 520 + kc * 64 + kc;
    float a = 0.f;
#pragma unroll
    for (int i = 0; i < 16; ++i) {
      float4 w = w4[i];
      a += w.x * hpp[i * 4] + w.y * hpp[i * 4 + 1] + w.z * hpp[i * 4 + 2] + w.w * hpp[i * 4 + 3];
    }
    a += __shfl_xor(a, 1);
    a += __shfl_xor(a, 2);
    a += __shfl_xor(a, 4);
    if (kc == 0) feats[(size_t)(p0 + pos) * KTAGS + tag] = a + bo;
  }
}

// ---------------- K4: single-wave Viterbi forward ----------------
__global__ __launch_bounds__(64) void viterbi_fwd(
    const float* __restrict__ feats, const float* __restrict__ trans,
    unsigned char* __restrict__ bptr, float* __restrict__ score_out,
    int* __restrict__ best_out)
{
  const int ln = threadIdx.x;
  const int i = ln & 31;   // my tag (replicated in both halves)
  const int jb = ln >> 5;  // j-block: lanes handle j = jb*16 + s

  float Tj[16];
#pragma unroll
  for (int s = 0; s < 16; ++s) Tj[s] = trans[i * 32 + jb * 16 + s];

  float fv = (i == START_TAG) ? 0.0f : NEGV;
  float pf = feats[i];

  for (int t = 0; t < T_LEN; ++t) {
    float cv[16];
    int cj[16];
#pragma unroll
    for (int s = 0; s < 16; ++s) {
      cv[s] = __shfl(fv, jb * 16 + s) + Tj[s];
      cj[s] = jb * 16 + s;
    }
    // register argmax tree; strict > keeps lower j on ties (numpy rule)
#pragma unroll
    for (int st = 1; st < 16; st <<= 1)
#pragma unroll
      for (int s = 0; s < 16; s += 2 * st)
        if (cv[s + st] > cv[s]) { cv[s] = cv[s + st]; cj[s] = cj[s + st]; }
    float v = cv[0];
    int bj = cj[0];
    float ov = __shfl_xor(v, 32);
    int oj = __shfl_xor(bj, 32);
    if (ov > v || (ov == v && oj < bj)) { v = ov; bj = oj; }

    float f = pf;
    int tn = (t + 1 < T_LEN) ? t + 1 : t;
    pf = feats[(size_t)tn * KTAGS + i];  // prefetch
    fv = v + f;
    if (jb == 0) bptr[(size_t)t * KTAGS + i] = (unsigned char)bj;
  }

  float v = fv + trans[STOP_TAG * 32 + i];
  int bi = i;
#pragma unroll
  for (int m = 1; m < 32; m <<= 1) {
    float ov = __shfl_xor(v, m);
    int oi = __shfl_xor(bi, m);
    if (ov > v || (ov == v && oi < bi)) { v = ov; bi = oi; }
  }
  if (ln == 0) { score_out[0] = v; best_out[0] = bi; }
}

// ---------------- K5: compose 32-step backtrace maps ----------------
__global__ __launch_bounds__(64) void vit_compose(
    const unsigned char* __restrict__ bptr, unsigned char* __restrict__ fmap)
{
  const int m = blockIdx.x;
  __shared__ unsigned char B[32 * 32];
  const int tid = threadIdx.x;
  const uint32_t* src = (const uint32_t*)(bptr + (size_t)m * 1024);
  uint32_t* dstw = (uint32_t*)B;
  for (int idx = tid; idx < 256; idx += 64) dstw[idx] = src[idx];
  __syncthreads();
  if (tid < 32) {
    int y = tid;
#pragma unroll
    for (int tt = 31; tt >= 0; --tt) y = B[tt * 32 + y];
    fmap[m * 32 + tid] = (unsigned char)y;
  }
}

// ---------------- K6: boundary walk + parallel expansion ----------------
__global__ __launch_bounds__(256) void vit_backtrace(
    const unsigned char* __restrict__ bptr, const unsigned char* __restrict__ fmap,
    const int* __restrict__ best, float* __restrict__ path_out)
{
  __shared__ unsigned char F[128 * 32];
  __shared__ unsigned char bound[128];
  const int tid = threadIdx.x;
  const uint32_t* src = (const uint32_t*)fmap;
  uint32_t* dstw = (uint32_t*)F;
  for (int idx = tid; idx < 1024; idx += 256) dstw[idx] = src[idx];
  __syncthreads();
  if (tid == 0) {
    int y = best[0];
    bound[127] = (unsigned char)y;
    for (int m = 127; m >= 1; --m) {
      y = F[m * 32 + y];
      bound[m - 1] = (unsigned char)y;
    }
  }
  __syncthreads();
  if (tid < 128) {
    const int m = tid;
    int y = bound[m];
    path_out[m * 32 + 31] = (float)y;
    for (int tt = 30; tt >= 0; --tt) {
      y = bptr[(size_t)(m * 32 + tt + 1) * 32 + y];
      path_out[m * 32 + tt] = (float)y;
    }
  }
}

extern "C" void kernel_launch(void* const* d_in, const int* in_sizes, int n_in,
                              void* d_out, int out_size, void* d_ws, size_t ws_size,
                              hipStream_t stream)
{
  const int* sent    = (const int*)d_in[0];
  const float* embed = (const float*)d_in[1];
  const float* Wih_f = (const float*)d_in[2];
  const float* Whh_f = (const float*)d_in[3];
  const float* b_f   = (const float*)d_in[4];
  const float* Wih_b = (const float*)d_in[5];
  const float* Whh_b = (const float*)d_in[6];
  const float* b_b   = (const float*)d_in[7];
  const float* W_out = (const float*)d_in[8];
  const float* b_out = (const float*)d_in[9];
  const float* trans = (const float*)d_in[10];
  const float* h0    = (const float*)d_in[11];
  const float* c0    = (const float*)d_in[12];

  float* W = (float*)d_ws;
  float* zxF = W;                                    // 16 MB
  float* zxB = zxF + (size_t)T_LEN * G4;             // 16 MB
  float* feats = zxB + (size_t)T_LEN * G4;           // 512 KB
  uint32_t* hhF32 = (uint32_t*)(feats + (size_t)T_LEN * KTAGS);  // 2 MB (bf16 pairs)
  uint32_t* hhB32 = hhF32 + (size_t)T_LEN * 128;     // 2 MB
  int* bestIdx = (int*)(hhB32 + (size_t)T_LEN * 128);
  unsigned char* bptr = (unsigned char*)(bestIdx + 16);  // 128 KB
  unsigned char* fmap = bptr + (size_t)T_LEN * KTAGS;    // 4 KB

  float* out = (float*)d_out;  // out[0]=path_score, out[1..4096]=path tags

  zx_gemm<<<dim3(T_LEN / 8, 2), 256, 0, stream>>>(sent, embed, Wih_f, b_f, Wih_b, b_b, zxF, zxB);
  lstm_kernel<<<2, 512, 0, stream>>>(Whh_f, Whh_b, h0, c0, zxF, zxB, hhF32, hhB32);
  feat_kernel<<<T_LEN / 8, 256, 0, stream>>>((const __hip_bfloat16*)hhF32,
                                             (const __hip_bfloat16*)hhB32,
                                             W_out, b_out, feats);
  viterbi_fwd<<<1, 64, 0, stream>>>(feats, trans, bptr, out, bestIdx);
  vit_compose<<<128, 64, 0, stream>>>(bptr, fmap);
  vit_backtrace<<<1, 256, 0, stream>>>(bptr, fmap, bestIdx, out + 1);
}